// Round 6
// baseline (147.481 us; speedup 1.0000x reference)
//
#include <hip/hip_runtime.h>
#include <hip/hip_bf16.h>
#include <math.h>

#define B_   8
#define C_   512
#define H_   96
#define W_   96
#define HW   9216
#define K_   64
#define PH   12
#define PW   12
#define NT   96     // n-tile per block in main kernel
#define CCH  32     // c-chunk
#define NBLK 96     // n-blocks per batch = HW/NT (768 blocks = 3/CU exact)

// ws layout (bytes). candV/candN alias the dead `part` region.
#define OFF_PARTIAL 0u                    // float[8][73728]  -- dead after k_select
#define OFF_CANDV   0u                    // float[512*NBLK]
#define OFF_CANDN   294912u               // int[512*NBLK]
#define OFF_DESC    2359296u              // float[B*C*K] layout [b][c][k]
#define OFF_ROWA    3407872u              // int[512]
#define OFF_COLA    3409920u              // int[512]
#define OFF_FLATA   3411968u              // int[512]
#define OFF_OFFR    3414016u              // int[512]
#define OFF_OFFC    3416064u              // int[512]

#define GLOAD_LDS16(g, l)                                                     \
    __builtin_amdgcn_global_load_lds(                                         \
        (const __attribute__((address_space(1))) unsigned int*)(g),           \
        (__attribute__((address_space(3))) unsigned int*)(l), 16, 0, 0)

// ---------------- kernel 1: partial channel sums (float4) ----------------
__global__ __launch_bounds__(256) void k_partial(const float* __restrict__ A,
                                                 float* __restrict__ part) {
    int idx4 = blockIdx.x * 256 + threadIdx.x;     // float4 index over b*HW/4
    int chunk = blockIdx.y;
    int b = idx4 / (HW / 4), hw4 = idx4 - b * (HW / 4);
    const float* p = A + ((size_t)(b * C_ + chunk * 64)) * HW + hw4 * 4;
    float4 s = make_float4(0.f, 0.f, 0.f, 0.f);
#pragma unroll
    for (int i = 0; i < 64; ++i) {
        float4 v = *(const float4*)&p[(size_t)i * HW];
        s.x += v.x; s.y += v.y; s.z += v.z; s.w += v.w;
    }
    *(float4*)&part[chunk * (B_ * HW) + b * HW + hw4 * 4] = s;
}

// ---------------- kernel 2: per-region argmax (first max) ----------------
__global__ void k_select(const float* __restrict__ part, int* __restrict__ rowA,
                         int* __restrict__ colA, int* __restrict__ flatA) {
    int k = blockIdx.x, b = blockIdx.y, lane = threadIdx.x;
    int gi = k >> 3, gj = k & 7;
    float bv = -1e30f; int bp = 1 << 20;
    for (int p = lane; p < PH * PW; p += 64) {
        int lr = p / PW, lc = p - lr * PW;
        int hw = (gi * PH + lr) * W_ + gj * PW + lc;
        float v = 0.f;
#pragma unroll
        for (int ch = 0; ch < 8; ++ch) v += part[ch * (B_ * HW) + b * HW + hw];
        if (v > bv || (v == bv && p < bp)) { bv = v; bp = p; }
    }
    for (int m = 1; m < 64; m <<= 1) {
        float ov = __shfl_xor(bv, m);
        int   op = __shfl_xor(bp, m);
        if (ov > bv || (ov == bv && op < bp)) { bv = ov; bp = op; }
    }
    if (lane == 0) {
        int lr = bp / PW, lc = bp - lr * PW;
        int r = gi * PH + lr, c = gj * PW + lc;
        rowA[b * K_ + k] = r; colA[b * K_ + k] = c; flatA[b * K_ + k] = r * W_ + c;
    }
}

// ---------------- kernel 3: gather descriptors desc[b][c][k] ----------------
__global__ __launch_bounds__(256) void k_gather(const float* __restrict__ A,
                                                const int* __restrict__ flatA,
                                                float* __restrict__ desc) {
    int idx = blockIdx.x * 256 + threadIdx.x;   // b(3b)|c(9b)|k(6b)
    int k = idx & 63, c = (idx >> 6) & 511, b = idx >> 15;
    desc[idx] = A[((size_t)(b * C_ + c)) * HW + flatA[(b << 6) + k]];
}

// ---------------- kernel 4: cross GEMM + fused argmin ----------------
// grid (NBLK=96, 8 batches), block 192 (3 waves). Thread tile: 8 k x 4 n.
// kg = tid/24 (0..7): k = kg*8+kk.  ng = tid%24: n = nb + ng*4 + j.
// fb staged to LDS via global_load_lds (double-buffered, DMA).
// desc read DIRECTLY from global: the 24 threads sharing a kg read the same
// 32 B -> coalescer dedups to ~3 requests/wave/c, L2-resident (1 MB total).
// This removes 2/3 of the LDS read traffic that capped VALUBusy at ~40-50%.
__global__ __launch_bounds__(192) void k_main(const float* __restrict__ FB,
                                              const float* __restrict__ desc,
                                              float* __restrict__ candV,
                                              int* __restrict__ candN) {
    __shared__ float smem[6144];           // two 12 KB buffers (32c x 96n fp32)
    int b = blockIdx.y, nb = blockIdx.x * NT;
    int tid = threadIdx.x;
    int kg = tid / 24, ng = tid - kg * 24;
    int w = tid >> 6;                      // wave id (0..2) -- wave-uniform
    int lane = tid & 63;
    const size_t baseB = (size_t)b * C_ * HW + nb;
    const float* descb = desc + (size_t)b * C_ * K_;

    float acc[8][4];
#pragma unroll
    for (int i = 0; i < 8; ++i)
#pragma unroll
        for (int j = 0; j < 4; ++j) acc[i][j] = 0.f;
    float4 sq4 = make_float4(0.f, 0.f, 0.f, 0.f);

    // staging: 12 wave-loads of 1 KB cover 32c x 96n; per-lane global source.
#define STAGE(bufofs, c0)                                                     \
    do {                                                                      \
        _Pragma("unroll")                                                     \
        for (int i = 0; i < 4; ++i) {                                         \
            int e = (w * 4 + i) * 256 + lane * 4;                             \
            int c = e / 96, n = e - c * 96;                                   \
            GLOAD_LDS16(&FB[baseB + (size_t)((c0) + c) * HW + n],             \
                        &smem[(bufofs) + (w * 4 + i) * 256]);                 \
        }                                                                     \
    } while (0)

    STAGE(0, 0);
    __syncthreads();

    for (int t = 0; t < C_ / CCH; ++t) {
        const int cur = (t & 1) ? 3072 : 0;
        if (t < C_ / CCH - 1) STAGE(cur ^ 3072, (t + 1) * CCH);
        const float* fbs = &smem[cur];
        const int c0 = t * CCH;
#pragma unroll 4
        for (int c = 0; c < CCH; ++c) {
            const float4 d0 = *(const float4*)&descb[(size_t)(c0 + c) * K_ + kg * 8];
            const float4 d1 = *(const float4*)&descb[(size_t)(c0 + c) * K_ + kg * 8 + 4];
            const float4 f0 = *(const float4*)&fbs[c * 96 + ng * 4];
            float dk[8] = {d0.x, d0.y, d0.z, d0.w, d1.x, d1.y, d1.z, d1.w};
            float fn[4] = {f0.x, f0.y, f0.z, f0.w};
#pragma unroll
            for (int kk = 0; kk < 8; ++kk)
#pragma unroll
                for (int j = 0; j < 4; ++j)
                    acc[kk][j] = fmaf(dk[kk], fn[j], acc[kk][j]);
        }
        // fbsq partial: thread (kg, ng) owns c-rows kg*4..+3 of column-quad ng
#pragma unroll
        for (int i = 0; i < 4; ++i) {
            const float4 v = *(const float4*)&fbs[(kg * 4 + i) * 96 + ng * 4];
            sq4.x = fmaf(v.x, v.x, sq4.x);
            sq4.y = fmaf(v.y, v.y, sq4.y);
            sq4.z = fmaf(v.z, v.z, sq4.z);
            sq4.w = fmaf(v.w, v.w, sq4.w);
        }
        __syncthreads();
    }

    // ---- epilogue scratch (both buffers dead) ----
    // pf[8][96] at 0..767 | fbsq_s[96] at 768..863 | bvs[64][24] at 1024..
    // bns[64][24] at 2560..
    *(float4*)&smem[kg * 96 + ng * 4] = sq4;
    __syncthreads();
    if (tid < 96) {
        float s = 0.f;
#pragma unroll
        for (int g = 0; g < 8; ++g) s += smem[g * 96 + tid];
        smem[768 + tid] = s;
    }
    __syncthreads();
    const float4 q0 = *(const float4*)&smem[768 + ng * 4];
    float fsq[4] = {q0.x, q0.y, q0.z, q0.w};
    int* bns = (int*)&smem[2560];
#pragma unroll
    for (int kk = 0; kk < 8; ++kk) {
        float bv = 1e30f; int bn = 1 << 28;
#pragma unroll
        for (int j = 0; j < 4; ++j) {          // n ascending within thread
            float sc = fsq[j] - 2.f * acc[kk][j];
            if (sc < bv) { bv = sc; bn = nb + ng * 4 + j; }
        }
        smem[1024 + (kg * 8 + kk) * 24 + ng] = bv;
        bns[(kg * 8 + kk) * 24 + ng] = bn;
    }
    __syncthreads();
    if (tid < K_) {
        float bv = 1e30f; int bn = 1 << 28;
        for (int j2 = 0; j2 < 24; ++j2) {      // ng ascending = n ascending
            float ov = smem[1024 + tid * 24 + j2];
            int   on = bns[tid * 24 + j2];
            if (ov < bv || (ov == bv && on < bn)) { bv = ov; bn = on; }
        }
        candV[(b * K_ + tid) * NBLK + blockIdx.x] = bv;
        candN[(b * K_ + tid) * NBLK + blockIdx.x] = bn;
    }
#undef STAGE
}

// ---------------- kernel 5: cross-block argmin + offsets ----------------
// grid (64, 8), block 64. NBLK=96 candidates per (b,k).
__global__ void k_reduce(const float* __restrict__ candV, const int* __restrict__ candN,
                         const int* __restrict__ rowA, const int* __restrict__ colA,
                         int* __restrict__ offR, int* __restrict__ offC) {
    int k = blockIdx.x, b = blockIdx.y, lane = threadIdx.x;
    int base = (b * K_ + k) * NBLK;
    float bv = candV[base + lane]; int bn = candN[base + lane];
    if (lane < NBLK - 64) {
        float ov = candV[base + 64 + lane]; int on = candN[base + 64 + lane];
        if (ov < bv || (ov == bv && on < bn)) { bv = ov; bn = on; }
    }
    for (int m = 1; m < 64; m <<= 1) {
        float ov = __shfl_xor(bv, m);
        int   on = __shfl_xor(bn, m);
        if (ov < bv || (ov == bv && on < bn)) { bv = ov; bn = on; }
    }
    if (lane == 0) {
        int rB = bn / W_, cB = bn - rB * W_;
        offR[b * K_ + k] = rowA[b * K_ + k] - rB;   // -(rowB - rowA)
        offC[b * K_ + k] = colA[b * K_ + k] - cB;
    }
}

// ---------------- kernel 6: per-batch mode (first-index tie-break) ----------------
__global__ void k_mode(const int* __restrict__ offR, const int* __restrict__ offC,
                       int* __restrict__ out) {
    __shared__ int r_s[64], c_s[64];
    int b = blockIdx.x, k = threadIdx.x;
    r_s[k] = offR[b * 64 + k]; c_s[k] = offC[b * 64 + k];
    __syncthreads();
    int mr = r_s[k], mc = c_s[k], cnt = 0;
#pragma unroll
    for (int j = 0; j < 64; ++j) cnt += (r_s[j] == mr && c_s[j] == mc) ? 1 : 0;
    int bk = k, bc = cnt;
    for (int m = 1; m < 64; m <<= 1) {
        int oc = __shfl_xor(bc, m);
        int ok = __shfl_xor(bk, m);
        if (oc > bc || (oc == bc && ok < bk)) { bc = oc; bk = ok; }
    }
    if (k == 0) { out[b * 2] = r_s[bk]; out[b * 2 + 1] = c_s[bk]; }
}

extern "C" void kernel_launch(void* const* d_in, const int* in_sizes, int n_in,
                              void* d_out, int out_size, void* d_ws, size_t ws_size,
                              hipStream_t stream) {
    const float* A  = (const float*)d_in[0];
    const float* FB = (const float*)d_in[1];
    char* ws = (char*)d_ws;
    float* part  = (float*)(ws + OFF_PARTIAL);
    float* desc  = (float*)(ws + OFF_DESC);
    int*   rowA  = (int*)(ws + OFF_ROWA);
    int*   colA  = (int*)(ws + OFF_COLA);
    int*   flatA = (int*)(ws + OFF_FLATA);
    float* candV = (float*)(ws + OFF_CANDV);
    int*   candN = (int*)(ws + OFF_CANDN);
    int*   offR  = (int*)(ws + OFF_OFFR);
    int*   offC  = (int*)(ws + OFF_OFFC);
    int*   out   = (int*)d_out;

    k_partial<<<dim3((B_ * HW) / 1024, 8), 256, 0, stream>>>(A, part);
    k_select<<<dim3(K_, B_), 64, 0, stream>>>(part, rowA, colA, flatA);
    k_gather<<<dim3((B_ * C_ * K_) / 256), 256, 0, stream>>>(A, flatA, desc);
    k_main<<<dim3(NBLK, B_), 192, 0, stream>>>(FB, desc, candV, candN);
    k_reduce<<<dim3(K_, B_), 64, 0, stream>>>(candV, candN, rowA, colA, offR, offC);
    k_mode<<<dim3(B_), 64, 0, stream>>>(offR, offC, out);
}

// Round 7
// 143.248 us; speedup vs baseline: 1.0295x; 1.0295x over previous
//
#include <hip/hip_runtime.h>
#include <hip/hip_bf16.h>
#include <math.h>

#define B_   8
#define C_   512
#define H_   96
#define W_   96
#define HW   9216
#define K_   64
#define PH   12
#define PW   12
#define NT   96     // n-tile per block in main kernel
#define NBLK 96     // n-blocks per batch (768 blocks = exactly 3/CU)

// ws layout (bytes). candV/candN alias the dead `part` region.
#define OFF_PARTIAL 0u                    // float[8][73728]  -- dead after k_selgather
#define OFF_CANDV   0u                    // float[512*NBLK]
#define OFF_CANDN   294912u               // int[512*NBLK]
#define OFF_DESC    2359296u              // float[B*C*K] layout [b][c][k]
#define OFF_ROWA    3407872u              // int[512]
#define OFF_COLA    3409920u              // int[512]

#define GLOAD_LDS16(g, l)                                                     \
    __builtin_amdgcn_global_load_lds(                                         \
        (const __attribute__((address_space(1))) unsigned int*)(g),           \
        (__attribute__((address_space(3))) unsigned int*)(l), 16, 0, 0)

// ---------------- kernel 1: partial channel sums (float4) ----------------
__global__ __launch_bounds__(256) void k_partial(const float* __restrict__ A,
                                                 float* __restrict__ part) {
    int idx4 = blockIdx.x * 256 + threadIdx.x;     // float4 index over b*HW/4
    int chunk = blockIdx.y;
    int b = idx4 / (HW / 4), hw4 = idx4 - b * (HW / 4);
    const float* p = A + ((size_t)(b * C_ + chunk * 64)) * HW + hw4 * 4;
    float4 s = make_float4(0.f, 0.f, 0.f, 0.f);
#pragma unroll
    for (int i = 0; i < 64; ++i) {
        float4 v = *(const float4*)&p[(size_t)i * HW];
        s.x += v.x; s.y += v.y; s.z += v.z; s.w += v.w;
    }
    *(float4*)&part[chunk * (B_ * HW) + b * HW + hw4 * 4] = s;
}

// ---------------- kernel 2: argmax select + descriptor gather ----------------
// grid (64 regions, 8 batches), block 64 (one wave).
__global__ void k_selgather(const float* __restrict__ part, const float* __restrict__ A,
                            int* __restrict__ rowA, int* __restrict__ colA,
                            float* __restrict__ desc) {
    int k = blockIdx.x, b = blockIdx.y, lane = threadIdx.x;
    int gi = k >> 3, gj = k & 7;
    float bv = -1e30f; int bp = 1 << 20;
    for (int p = lane; p < PH * PW; p += 64) {
        int lr = p / PW, lc = p - lr * PW;
        int hw = (gi * PH + lr) * W_ + gj * PW + lc;
        float v = 0.f;
#pragma unroll
        for (int ch = 0; ch < 8; ++ch) v += part[ch * (B_ * HW) + b * HW + hw];
        if (v > bv || (v == bv && p < bp)) { bv = v; bp = p; }
    }
    for (int m = 1; m < 64; m <<= 1) {      // butterfly: all lanes end with winner
        float ov = __shfl_xor(bv, m);
        int   op = __shfl_xor(bp, m);
        if (ov > bv || (ov == bv && op < bp)) { bv = ov; bp = op; }
    }
    int lr = bp / PW, lc = bp - lr * PW;
    int r = gi * PH + lr, c = gj * PW + lc;
    int flat = r * W_ + c;
    if (lane == 0) { rowA[b * K_ + k] = r; colA[b * K_ + k] = c; }
    // gather this keypoint's descriptor: desc[b][c][k], c = i*64+lane
#pragma unroll
    for (int i = 0; i < 8; ++i) {
        int cc = i * 64 + lane;
        desc[((size_t)(b * C_ + cc)) * K_ + k] = A[((size_t)(b * C_ + cc)) * HW + flat];
    }
}

// ---------------- kernel 3: cross GEMM + fused argmin ----------------
// grid (96, 8), block 256 (4 waves). Two c-halves of 128 threads each:
// half h covers c in [h*256, h*256+256). Within a half: hkg=th>>4 (8 k-groups
// of 8), hng=th&15 (16 n-groups of 6). Thread tile 8k x 6n = 48 acc.
// LDS bytes/FMA = (8+6)*4/48 = 1.17 -> VALU-bound (LDS return BW model).
// Staging: global_load_lds dbuf per half. Halves combine acc via LDS exchange.
__global__ __launch_bounds__(256, 2) void k_main(const float* __restrict__ FB,
                                                 const float* __restrict__ desc,
                                                 float* __restrict__ candV,
                                                 int* __restrict__ candN) {
    __shared__ float smem[10240];          // 40 KB: 4 units of 2560 (fb1536+dsk1024)
    int b = blockIdx.y, nb = blockIdx.x * NT;
    int tid = threadIdx.x;
    int h = tid >> 7;                      // c-half
    int th = tid & 127;
    int hw = th >> 6;                      // wave within half (0/1)
    int hlane = tid & 63;
    int hkg = th >> 4, hng = th & 15;
    const size_t baseB = (size_t)b * C_ * HW + nb;
    const float* descb = desc + (size_t)b * C_ * K_;

    float acc[8][6];
#pragma unroll
    for (int i = 0; i < 8; ++i)
#pragma unroll
        for (int j = 0; j < 6; ++j) acc[i][j] = 0.f;
    float sqa = 0.f;

    // stage one 16c chunk for half h into unit at float-offset `base`
#define STAGE(base, c0)                                                       \
    do {                                                                      \
        _Pragma("unroll")                                                     \
        for (int i = 0; i < 3; ++i) {      /* fb: 16c x 96n = 1536 floats */  \
            int e = (hw * 3 + i) * 256 + hlane * 4;                           \
            int cc = e / 96, nn = e - cc * 96;                                \
            GLOAD_LDS16(&FB[baseB + (size_t)((c0) + cc) * HW + nn],           \
                        &smem[(base) + (hw * 3 + i) * 256]);                  \
        }                                                                     \
        _Pragma("unroll")                                                     \
        for (int i = 0; i < 2; ++i) {      /* dsk: 16c x 64k = 1024 floats */ \
            int e = (hw * 2 + i) * 256 + hlane * 4;                           \
            int cc = e >> 6, kq = e & 63;                                     \
            GLOAD_LDS16(&descb[(size_t)((c0) + cc) * K_ + kq],                \
                        &smem[(base) + 1536 + (hw * 2 + i) * 256]);           \
        }                                                                     \
    } while (0)

    const int ub = h * 5120;               // this half's unit pair
    STAGE(ub, h * 256);
    __syncthreads();

    for (int t = 0; t < 16; ++t) {
        const int cur = ub + (t & 1) * 2560;
        if (t < 15) STAGE(ub + ((t & 1) ^ 1) * 2560, h * 256 + (t + 1) * 16);
        const float* fbs = &smem[cur];
        const float* dsk = &smem[cur + 1536];
#pragma unroll 4
        for (int c = 0; c < 16; ++c) {
            const float4 d0 = *(const float4*)&dsk[c * 64 + hkg * 8];
            const float4 d1 = *(const float4*)&dsk[c * 64 + hkg * 8 + 4];
            const float2 f0 = *(const float2*)&fbs[c * 96 + hng * 6];
            const float2 f1 = *(const float2*)&fbs[c * 96 + hng * 6 + 2];
            const float2 f2 = *(const float2*)&fbs[c * 96 + hng * 6 + 4];
            float dk[8] = {d0.x, d0.y, d0.z, d0.w, d1.x, d1.y, d1.z, d1.w};
            float fn[6] = {f0.x, f0.y, f1.x, f1.y, f2.x, f2.y};
#pragma unroll
            for (int kk = 0; kk < 8; ++kk)
#pragma unroll
                for (int j = 0; j < 6; ++j)
                    acc[kk][j] = fmaf(dk[kk], fn[j], acc[kk][j]);
        }
        // fbsq partial: thread th<96 owns column th within this half's c-range
        if (th < 96) {
#pragma unroll
            for (int i = 0; i < 16; ++i) {
                float v = fbs[i * 96 + th];
                sqa = fmaf(v, v, sqa);
            }
        }
        __syncthreads();
    }

    // ---- epilogue: combine halves (all staging buffers dead) ----
    float* ex   = smem;                    // [128][49] padded exchange
    float* fq0  = &smem[6400];             // [96]
    float* fq1  = &smem[6500];             // [96]
    float* bvs  = &smem[6656];             // [64][16]
    int*   bns  = (int*)&smem[7680];       // [64][16]
    if (h == 1) {
#pragma unroll
        for (int kk = 0; kk < 8; ++kk)
#pragma unroll
            for (int j = 0; j < 6; ++j) ex[th * 49 + kk * 6 + j] = acc[kk][j];
    }
    if (th < 96) (h ? fq1 : fq0)[th] = sqa;
    __syncthreads();
    if (h == 0) {
#pragma unroll
        for (int kk = 0; kk < 8; ++kk)
#pragma unroll
            for (int j = 0; j < 6; ++j) acc[kk][j] += ex[th * 49 + kk * 6 + j];
        float fsq[6];
#pragma unroll
        for (int j = 0; j < 6; ++j) {
            int n = hng * 6 + j;
            fsq[j] = fq0[n] + fq1[n];
        }
#pragma unroll
        for (int kk = 0; kk < 8; ++kk) {
            float bv = 1e30f; int bn = 1 << 28;
#pragma unroll
            for (int j = 0; j < 6; ++j) {      // n ascending -> first-min
                float sc = fsq[j] - 2.f * acc[kk][j];
                if (sc < bv) { bv = sc; bn = nb + hng * 6 + j; }
            }
            bvs[(hkg * 8 + kk) * 16 + hng] = bv;
            bns[(hkg * 8 + kk) * 16 + hng] = bn;
        }
    }
    __syncthreads();
    if (tid < K_) {
        float bv = 1e30f; int bn = 1 << 28;
        for (int j2 = 0; j2 < 16; ++j2) {      // hng ascending = n ascending
            float ov = bvs[tid * 16 + j2];
            int   on = bns[tid * 16 + j2];
            if (ov < bv || (ov == bv && on < bn)) { bv = ov; bn = on; }
        }
        candV[(b * K_ + tid) * NBLK + blockIdx.x] = bv;
        candN[(b * K_ + tid) * NBLK + blockIdx.x] = bn;
    }
#undef STAGE
}

// ---------------- kernel 4: cross-block argmin + offsets + mode ----------------
// grid (8), block 64. Thread k scans 96 candidates, then in-block mode.
__global__ void k_redmode(const float* __restrict__ candV, const int* __restrict__ candN,
                          const int* __restrict__ rowA, const int* __restrict__ colA,
                          int* __restrict__ out) {
    __shared__ int r_s[64], c_s[64];
    int b = blockIdx.x, k = threadIdx.x;
    int base = (b * K_ + k) * NBLK;
    float bv = 1e30f; int bn = 1 << 28;
    for (int j = 0; j < NBLK; ++j) {
        float ov = candV[base + j]; int on = candN[base + j];
        if (ov < bv || (ov == bv && on < bn)) { bv = ov; bn = on; }
    }
    int rB = bn / W_, cB = bn - rB * W_;
    r_s[k] = rowA[b * K_ + k] - rB;        // -(rowB - rowA)
    c_s[k] = colA[b * K_ + k] - cB;
    __syncthreads();
    int mr = r_s[k], mc = c_s[k], cnt = 0;
#pragma unroll
    for (int j = 0; j < 64; ++j) cnt += (r_s[j] == mr && c_s[j] == mc) ? 1 : 0;
    int bk = k, bc = cnt;
    for (int m = 1; m < 64; m <<= 1) {
        int oc = __shfl_xor(bc, m);
        int ok = __shfl_xor(bk, m);
        if (oc > bc || (oc == bc && ok < bk)) { bc = oc; bk = ok; }
    }
    if (k == 0) { out[b * 2] = r_s[bk]; out[b * 2 + 1] = c_s[bk]; }
}

extern "C" void kernel_launch(void* const* d_in, const int* in_sizes, int n_in,
                              void* d_out, int out_size, void* d_ws, size_t ws_size,
                              hipStream_t stream) {
    const float* A  = (const float*)d_in[0];
    const float* FB = (const float*)d_in[1];
    char* ws = (char*)d_ws;
    float* part  = (float*)(ws + OFF_PARTIAL);
    float* desc  = (float*)(ws + OFF_DESC);
    int*   rowA  = (int*)(ws + OFF_ROWA);
    int*   colA  = (int*)(ws + OFF_COLA);
    float* candV = (float*)(ws + OFF_CANDV);
    int*   candN = (int*)(ws + OFF_CANDN);
    int*   out   = (int*)d_out;

    k_partial<<<dim3((B_ * HW) / 1024, 8), 256, 0, stream>>>(A, part);
    k_selgather<<<dim3(K_, B_), 64, 0, stream>>>(part, A, rowA, colA, desc);
    k_main<<<dim3(NBLK, B_), 256, 0, stream>>>(FB, desc, candV, candN);
    k_redmode<<<dim3(B_), 64, 0, stream>>>(candV, candN, rowA, colA, out);
}

// Round 9
// 93.576 us; speedup vs baseline: 1.5760x; 1.5308x over previous
//
#include <hip/hip_runtime.h>
#include <hip/hip_bf16.h>
#include <math.h>

typedef _Float16 half8 __attribute__((ext_vector_type(8)));
typedef float f32x4 __attribute__((ext_vector_type(4)));
typedef unsigned short u16x4 __attribute__((ext_vector_type(4)));

#define B_   8
#define C_   512
#define H_   96
#define W_   96
#define HW   9216
#define K_   64
#define PH   12
#define PW   12
#define NT   96     // n-tile per block in k_main
#define CCH  32     // c-chunk
#define NBLK 96     // n-blocks per batch (768 blocks = 3/CU exact)

// ws layout (bytes). candV/candN alias the dead `part` region.
#define OFF_PARTIAL 0u                    // float[8][73728]  -- dead after k_selgather
#define OFF_CANDV   0u                    // float[512*NBLK]
#define OFF_CANDN   294912u               // int[512*NBLK]
#define OFF_DESCH   2359296u              // _Float16[B*K*C]  ([b][k][c], hi)
#define OFF_DESCL   2883584u              // _Float16[B*K*C]  (lo * 2048)
#define OFF_ROWA    3407872u              // int[512]
#define OFF_COLA    3409920u              // int[512]

// k_main LDS halfword offsets within one buffer (BUFHW halfwords/buffer):
//   FBT_HI: [nt:6][phys_c:32][nn:16]  (phys_c = tr_read row permutation)
//   DSC_*:  [k:64][c:32] linear
#define FBT_HI 0
#define FBT_LO 3072
#define DSC_HI 6144
#define DSC_LO 8192
#define BUFHW  10240

#define GLOAD_LDS16(g, l)                                                     \
    __builtin_amdgcn_global_load_lds(                                         \
        (const __attribute__((address_space(1))) unsigned int*)(g),           \
        (__attribute__((address_space(3))) unsigned int*)(l), 16, 0, 0)

// ---------------- kernel 1: partial channel sums (float4) ----------------
__global__ __launch_bounds__(256) void k_partial(const float* __restrict__ A,
                                                 float* __restrict__ part) {
    int idx4 = blockIdx.x * 256 + threadIdx.x;
    int chunk = blockIdx.y;
    int b = idx4 / (HW / 4), hw4 = idx4 - b * (HW / 4);
    const float* p = A + ((size_t)(b * C_ + chunk * 64)) * HW + hw4 * 4;
    float4 s = make_float4(0.f, 0.f, 0.f, 0.f);
#pragma unroll
    for (int i = 0; i < 64; ++i) {
        float4 v = *(const float4*)&p[(size_t)i * HW];
        s.x += v.x; s.y += v.y; s.z += v.z; s.w += v.w;
    }
    *(float4*)&part[chunk * (B_ * HW) + b * HW + hw4 * 4] = s;
}

// ---------------- kernel 2: argmax select + split-f16 descriptor gather ----
// grid (64 regions, 8 batches), block 64. Writes descT hi/lo in [b][k][c].
__global__ void k_selgather(const float* __restrict__ part, const float* __restrict__ A,
                            int* __restrict__ rowA, int* __restrict__ colA,
                            _Float16* __restrict__ descH, _Float16* __restrict__ descL) {
    int k = blockIdx.x, b = blockIdx.y, lane = threadIdx.x;
    int gi = k >> 3, gj = k & 7;
    float bv = -1e30f; int bp = 1 << 20;
    for (int p = lane; p < PH * PW; p += 64) {
        int lr = p / PW, lc = p - lr * PW;
        int hw = (gi * PH + lr) * W_ + gj * PW + lc;
        float v = 0.f;
#pragma unroll
        for (int ch = 0; ch < 8; ++ch) v += part[ch * (B_ * HW) + b * HW + hw];
        if (v > bv || (v == bv && p < bp)) { bv = v; bp = p; }
    }
    for (int m = 1; m < 64; m <<= 1) {
        float ov = __shfl_xor(bv, m);
        int   op = __shfl_xor(bp, m);
        if (ov > bv || (ov == bv && op < bp)) { bv = ov; bp = op; }
    }
    int lr = bp / PW, lc = bp - lr * PW;
    int r = gi * PH + lr, c = gj * PW + lc;
    int flat = r * W_ + c;
    if (lane == 0) { rowA[b * K_ + k] = r; colA[b * K_ + k] = c; }
#pragma unroll
    for (int i = 0; i < 8; ++i) {
        int cc = i * 64 + lane;
        float v = A[((size_t)(b * C_ + cc)) * HW + flat];
        _Float16 h = (_Float16)v;
        _Float16 lo = (_Float16)((v - (float)h) * 2048.f);
        size_t o = ((size_t)(b * K_ + k)) * C_ + cc;
        descH[o] = h; descL[o] = lo;
    }
}

// ---------------- kernel 3: MFMA cross GEMM + fused argmin ----------------
// grid (96, 8), block 256 (4 waves). M=keypoints(64: wave w owns 16),
// N=n (96: 6 tiles of 16), K=c. mfma_f32_16x16x32_f16, fp32-split:
// x = hi + lo/2048; cross = accHH + accX/2048 (accX = hi*lo' + lo*hi').
// fb: fp32 global -> regs -> convert -> permuted LDS; B-frags via
// ds_read_b64_tr_b16 with NATURAL per-lane addressing (addr_l = base + l*8B;
// each 16-lane group transposes its 128B block: lane l elem j =
// hw[base + (l>>4)*64 + j*16 + (l&15)]). The c-row store permutation
// phys = 16*(r>=4) + 4*(c>>3) + (r&3)  (r = c&7) makes the delivered
// elements exactly the A/B octet layout k = 8*(l>>4)+j.
__global__ __launch_bounds__(256, 3) void k_main(const float* __restrict__ FB,
                                                 const _Float16* __restrict__ descH,
                                                 const _Float16* __restrict__ descL,
                                                 float* __restrict__ candV,
                                                 int* __restrict__ candN) {
    __shared__ __attribute__((aligned(16))) unsigned short smem_us[2 * BUFHW];
    int b = blockIdx.y, nb = blockIdx.x * NT;
    int tid = threadIdx.x;
    int l = tid & 63;
    int w = tid >> 6;                          // wave id 0..3 (M-tile)
    const size_t baseB = (size_t)b * C_ * HW + nb;

    // fb staging map (threads 0..191): n-octet so, base c = scb (+pass*16)
    const int so = tid % 12;
    const int scb = tid / 12;
    const int st_nt = so >> 1, st_nn0 = (so & 1) * 8;

    // desc staging per-lane global src (wave w covers k rows w*16..w*16+15)
    const _Float16* dH = descH + ((size_t)(b * K_) + w * 16 + (l >> 2)) * C_ + (l & 3) * 8;
    const _Float16* dL = descL + ((size_t)(b * K_) + w * 16 + (l >> 2)) * C_ + (l & 3) * 8;

    f32x4 accH[6], accX[6];
#pragma unroll
    for (int nt = 0; nt < 6; ++nt) {
        accH[nt] = (f32x4){0.f, 0.f, 0.f, 0.f};
        accX[nt] = (f32x4){0.f, 0.f, 0.f, 0.f};
    }
    float sq[8];
#pragma unroll
    for (int j = 0; j < 8; ++j) sq[j] = 0.f;

    float4 r0a, r0b, r1a, r1b;                 // staged fb regs (2 passes)

#define LOADFB(c0)                                                            \
    do {                                                                      \
        if (tid < 192) {                                                      \
            const float* p0 = &FB[baseB + (size_t)((c0) + scb) * HW + so * 8];      \
            const float* p1 = &FB[baseB + (size_t)((c0) + scb + 16) * HW + so * 8]; \
            r0a = *(const float4*)p0; r0b = *(const float4*)(p0 + 4);         \
            r1a = *(const float4*)p1; r1b = *(const float4*)(p1 + 4);         \
        }                                                                     \
    } while (0)

#define CVT8(va, vb, hofs)                                                    \
    do {                                                                      \
        float vv[8] = {va.x, va.y, va.z, va.w, vb.x, vb.y, vb.z, vb.w};       \
        half8 h8, l8;                                                         \
        _Pragma("unroll")                                                     \
        for (int j = 0; j < 8; ++j) {                                         \
            float v = vv[j];                                                  \
            _Float16 hh = (_Float16)v;                                        \
            l8[j] = (_Float16)((v - (float)hh) * 2048.f);                     \
            h8[j] = hh;                                                       \
            sq[j] = fmaf(v, v, sq[j]);                                        \
        }                                                                     \
        *(half8*)&smem_us[(hofs)] = h8;                                       \
        *(half8*)&smem_us[(hofs) + FBT_LO] = l8;                              \
    } while (0)

#define WRITEFB(bufhw)                                                        \
    do {                                                                      \
        if (tid < 192) {                                                      \
            int c = scb;                                                      \
            int off0 = (bufhw) + FBT_HI + st_nt * 512 + ((c >> 2) & 1) * 256  \
                       + (c >> 3) * 64 + (c & 3) * 16 + st_nn0;               \
            CVT8(r0a, r0b, off0);                                             \
            c = scb + 16;                                                     \
            int off1 = (bufhw) + FBT_HI + st_nt * 512 + ((c >> 2) & 1) * 256  \
                       + (c >> 3) * 64 + (c & 3) * 16 + st_nn0;               \
            CVT8(r1a, r1b, off1);                                             \
        }                                                                     \
    } while (0)

#define STAGEDESC(bufhw, c0)                                                  \
    do {                                                                      \
        GLOAD_LDS16(dH + (c0), &smem_us[(bufhw) + DSC_HI + w * 512]);         \
        GLOAD_LDS16(dL + (c0), &smem_us[(bufhw) + DSC_LO + w * 512]);         \
    } while (0)

    LOADFB(0);
    STAGEDESC(0, 0);
    WRITEFB(0);
    __syncthreads();

    const unsigned lds0 = (unsigned)(size_t)&smem_us[0];
    const unsigned trlane = (unsigned)l * 8u;   // NATURAL per-lane addressing

    for (int t = 0; t < 16; ++t) {
        const int cur = (t & 1) ? BUFHW : 0;
        const int nxt = BUFHW - cur;
        if (t < 15) { LOADFB((t + 1) * CCH); STAGEDESC(nxt, (t + 1) * CCH); }

        // A fragments: descT[k][c] linear b128 reads
        half8 aH = *(half8*)&smem_us[cur + DSC_HI + (w * 16 + (l & 15)) * 32 + (l >> 4) * 8];
        half8 aL = *(half8*)&smem_us[cur + DSC_LO + (w * 16 + (l & 15)) * 32 + (l >> 4) * 8];
        const unsigned trb = lds0 + (unsigned)(cur + FBT_HI) * 2u + trlane;
#pragma unroll
        for (int nt = 0; nt < 6; ++nt) {
            u16x4 h0, h1, q0, q1;
            unsigned a0 = trb + (unsigned)nt * 1024u;
            asm volatile("ds_read_b64_tr_b16 %0, %1" : "=v"(h0) : "v"(a0));
            asm volatile("ds_read_b64_tr_b16 %0, %1 offset:512" : "=v"(h1) : "v"(a0));
            asm volatile("ds_read_b64_tr_b16 %0, %1 offset:6144" : "=v"(q0) : "v"(a0));
            asm volatile("ds_read_b64_tr_b16 %0, %1 offset:6656" : "=v"(q1) : "v"(a0));
            asm volatile("s_waitcnt lgkmcnt(0)" ::: "memory");
            __builtin_amdgcn_sched_barrier(0);
            union { u16x4 q[2]; half8 h; } uH, uL;
            uH.q[0] = h0; uH.q[1] = h1;
            uL.q[0] = q0; uL.q[1] = q1;
            accH[nt] = __builtin_amdgcn_mfma_f32_16x16x32_f16(aH, uH.h, accH[nt], 0, 0, 0);
            accX[nt] = __builtin_amdgcn_mfma_f32_16x16x32_f16(aH, uL.h, accX[nt], 0, 0, 0);
            accX[nt] = __builtin_amdgcn_mfma_f32_16x16x32_f16(aL, uH.h, accX[nt], 0, 0, 0);
        }
        if (t < 15) WRITEFB(nxt);
        __syncthreads();
    }

    // ---- epilogue (buffer 0 dead: floats 0..1631 reused as scratch) ----
    float* fscr = (float*)&smem_us[0];
    if (tid < 192) {
        *(float4*)&fscr[scb * 96 + so * 8]     = make_float4(sq[0], sq[1], sq[2], sq[3]);
        *(float4*)&fscr[scb * 96 + so * 8 + 4] = make_float4(sq[4], sq[5], sq[6], sq[7]);
    }
    __syncthreads();
    if (tid < 96) {
        float s = 0.f;
#pragma unroll
        for (int g = 0; g < 16; ++g) s += fscr[g * 96 + tid];
        fscr[1536 + tid] = s;
    }
    __syncthreads();

    const float inv2048 = 1.f / 2048.f;
#pragma unroll
    for (int r = 0; r < 4; ++r) {
        float bv = 1e30f; int bn = 1 << 28;
#pragma unroll
        for (int nt = 0; nt < 6; ++nt) {       // nt ascending -> n ascending
            float cross = accH[nt][r] + accX[nt][r] * inv2048;
            float d = fscr[1536 + nt * 16 + (l & 15)] - 2.f * cross;
            int n = nb + nt * 16 + (l & 15);
            if (d < bv) { bv = d; bn = n; }
        }
#pragma unroll
        for (int m = 1; m < 16; m <<= 1) {     // reduce the 16 n-lanes
            float ov = __shfl_xor(bv, m);
            int   on = __shfl_xor(bn, m);
            if (ov < bv || (ov == bv && on < bn)) { bv = ov; bn = on; }
        }
        if ((l & 15) == 0) {
            int k = w * 16 + (l >> 4) * 4 + r;
            candV[(b * K_ + k) * NBLK + blockIdx.x] = bv;
            candN[(b * K_ + k) * NBLK + blockIdx.x] = bn;
        }
    }
#undef LOADFB
#undef CVT8
#undef WRITEFB
#undef STAGEDESC
}

// ---------------- kernel 4: cross-block argmin + offsets + mode ----------------
__global__ void k_redmode(const float* __restrict__ candV, const int* __restrict__ candN,
                          const int* __restrict__ rowA, const int* __restrict__ colA,
                          int* __restrict__ out) {
    __shared__ int r_s[64], c_s[64];
    int b = blockIdx.x, k = threadIdx.x;
    int base = (b * K_ + k) * NBLK;
    float bv = 1e30f; int bn = 1 << 28;
    for (int j = 0; j < NBLK; ++j) {
        float ov = candV[base + j]; int on = candN[base + j];
        if (ov < bv || (ov == bv && on < bn)) { bv = ov; bn = on; }
    }
    int rB = bn / W_, cB = bn - rB * W_;
    r_s[k] = rowA[b * K_ + k] - rB;
    c_s[k] = colA[b * K_ + k] - cB;
    __syncthreads();
    int mr = r_s[k], mc = c_s[k], cnt = 0;
#pragma unroll
    for (int j = 0; j < 64; ++j) cnt += (r_s[j] == mr && c_s[j] == mc) ? 1 : 0;
    int bk = k, bc = cnt;
    for (int m = 1; m < 64; m <<= 1) {
        int oc = __shfl_xor(bc, m);
        int ok = __shfl_xor(bk, m);
        if (oc > bc || (oc == bc && ok < bk)) { bc = oc; bk = ok; }
    }
    if (k == 0) { out[b * 2] = r_s[bk]; out[b * 2 + 1] = c_s[bk]; }
}

extern "C" void kernel_launch(void* const* d_in, const int* in_sizes, int n_in,
                              void* d_out, int out_size, void* d_ws, size_t ws_size,
                              hipStream_t stream) {
    const float* A  = (const float*)d_in[0];
    const float* FB = (const float*)d_in[1];
    char* ws = (char*)d_ws;
    float*     part  = (float*)(ws + OFF_PARTIAL);
    _Float16*  descH = (_Float16*)(ws + OFF_DESCH);
    _Float16*  descL = (_Float16*)(ws + OFF_DESCL);
    int*       rowA  = (int*)(ws + OFF_ROWA);
    int*       colA  = (int*)(ws + OFF_COLA);
    float*     candV = (float*)(ws + OFF_CANDV);
    int*       candN = (int*)(ws + OFF_CANDN);
    int*       out   = (int*)d_out;

    k_partial<<<dim3((B_ * HW) / 1024, 8), 256, 0, stream>>>(A, part);
    k_selgather<<<dim3(K_, B_), 64, 0, stream>>>(part, A, rowA, colA, descH, descL);
    k_main<<<dim3(NBLK, B_), 256, 0, stream>>>(FB, descH, descL, candV, candN);
    k_redmode<<<dim3(B_), 64, 0, stream>>>(candV, candN, rowA, colA, out);
}